// Round 10
// baseline (244.114 us; speedup 1.0000x reference)
//
#include <hip/hip_runtime.h>
#include <math.h>

#define BB 64
#define QQ 32
#define DD 4096
#define EE 300
#define EPAD 320         // qn k-padded with zeros to 320 (10 chunks of 32)
#define NB 30
#define TDB 128          // doc rows per block
#define NDT (DD/TDB)     // 32
#define KC 32            // floats per K-chunk
#define NCH 10

typedef __attribute__((ext_vector_type(8))) short short8v;   // 8 bf16 = 1 MFMA frag
typedef __attribute__((ext_vector_type(4))) float f32x4;

// RNE float->bf16 (bit pattern), and bf16->float
static __device__ __forceinline__ unsigned short f2bf(float x) {
    unsigned int u = __builtin_bit_cast(unsigned int, x);
    u = (u + 0x7FFFu + ((u >> 16) & 1u)) >> 16;
    return (unsigned short)u;
}
static __device__ __forceinline__ float bf2f(unsigned short h) {
    return __builtin_bit_cast(float, (unsigned int)h << 16);
}

// ---------------- prep: normalize query, split to bf16 hi/lo, gate logits, zero hist ----
__global__ __launch_bounds__(64) void drmm_prep(const float* __restrict__ query,
                                                const float* __restrict__ Wg,
                                                const float* __restrict__ bg,
                                                unsigned short* __restrict__ qh,
                                                unsigned short* __restrict__ ql,
                                                float* __restrict__ glog,
                                                int* __restrict__ ghist) {
    const int row  = blockIdx.x;          // b*32+q
    const int lane = threadIdx.x;         // 0..63
    if (lane < NB) ghist[(size_t)row * NB + lane] = 0;   // replaces memset dispatch
    const float* src = query + (size_t)row * EE;
    float ss = 0.f;
    for (int e = lane; e < EE; e += 64) { float x = src[e]; ss += x * x; }
    for (int o = 1; o < 64; o <<= 1) ss += __shfl_xor(ss, o);
    const float inv = 1.0f / sqrtf(ss);
    float gd = 0.f;
    #pragma unroll
    for (int it = 0; it < 5; ++it) {      // 5*64 = 320 = EPAD
        int e = it * 64 + lane;
        float x = (e < EE) ? src[e] * inv : 0.f;
        unsigned short h = f2bf(x);
        float lo = x - bf2f(h);
        qh[(size_t)row * EPAD + e] = h;
        ql[(size_t)row * EPAD + e] = f2bf(lo);
        if (e < EE) gd += x * Wg[e];
    }
    for (int o = 1; o < 64; o <<= 1) gd += __shfl_xor(gd, o);
    if (lane == 0) glog[row] = gd + bg[0];
}

// ---------------- main: LDS-staged doc + direct-global qn MFMA + histogram ----------------
// 256 threads = 4 waves; wave wv owns doc rows [wv*32,+32) of the block's 128-row
// tile (2 MFMA tiles of 16). Per 32-float chunk: doc staged via 4 global_load_lds
// per thread (XOR-swizzled source, linear dest), qn A-fragments loaded DIRECTLY
// global->VGPR (L2-hot), register-double-buffered across even/odd bodies.
// Counted vmcnt(8/6); 2 barriers/chunk. LDS exactly 32 KB -> 5 blocks/CU.
__global__ __launch_bounds__(256, 5) void drmm_main(const float* __restrict__ doc,
                                                    const int* __restrict__ qlen,
                                                    const unsigned short* __restrict__ qh,
                                                    const unsigned short* __restrict__ ql,
                                                    int* __restrict__ ghist) {
    __shared__ __align__(16) float s_doc[2][TDB * KC];   // 2 x 16 KB (hist aliases later)

    const int b   = blockIdx.x >> 5;
    const int dt  = blockIdx.x & 31;
    const int len = __builtin_amdgcn_readfirstlane(qlen[b]);
    if (len == 0) return;                 // hist stays zero (prep zeroed ghist)

    const int tid = threadIdx.x;
    const int wv  = tid >> 6;             // wave id (uniform)
    const int l15 = tid & 15;             // fragment row index
    const int l4  = (tid >> 4) & 3;       // k-window (0..3), 8 floats each
    const int nqt = (len > 16) ? 2 : 1;   // q-tiles needed (scalar)

    const float* docb = doc + ((size_t)b * DD + dt * TDB) * EE;
    const unsigned short* qhb = qh + ((size_t)b * QQ + l15) * EPAD + l4 * 8;
    const unsigned short* qlb = ql + ((size_t)b * QQ + l15) * EPAD + l4 * 8;

    // stage doc chunk c into buffer buf: 4 global_load_lds per thread.
    // 1024 16B-slots; slot S=i*256+tid -> row r=S>>3, phys slot p=S&7 holds
    // logical slot p^(r&7) (inverse-swizzled source, linear LDS dest).
    auto STAGE = [&](int c, int buf) {
        #pragma unroll
        for (int i = 0; i < 4; ++i) {
            int S  = i * 256 + tid;
            int r  = S >> 3;
            int lg = (S & 7) ^ (r & 7);
            int kk = c * KC + 4 * lg;
            if (kk >= EE) kk = 0;         // pad slot: redirect in-bounds (qn pad=0)
            __builtin_amdgcn_global_load_lds(
                (const __attribute__((address_space(1))) void*)(docb + (size_t)r * EE + kk),
                (__attribute__((address_space(3))) void*)&s_doc[buf][(i * 256 + wv * 64) * 4],
                16, 0, 0);
        }
    };
    // load qn A-fragments for chunk c (direct global, L2-hot)
    auto LOADQ = [&](int c, short8v (&ah)[2], short8v (&al)[2]) {
        ah[0] = *(const short8v*)(qhb + c * KC);
        al[0] = *(const short8v*)(qlb + c * KC);
        if (nqt > 1) {
            ah[1] = *(const short8v*)(qhb + 16 * EPAD + c * KC);
            al[1] = *(const short8v*)(qlb + 16 * EPAD + c * KC);
        }
    };

    f32x4 acc[2][2];
    #pragma unroll
    for (int qt = 0; qt < 2; ++qt)
        #pragma unroll
        for (int t = 0; t < 2; ++t) acc[qt][t] = (f32x4){0.f, 0.f, 0.f, 0.f};
    float ssq[2] = {0.f, 0.f};

    // compute chunk c from buffer buf with pre-loaded qn fragments
    auto BODY = [&](int c, int buf, const short8v (&ah)[2], const short8v (&al)[2]) {
        const int kb = c * KC + l4 * 8;
        const bool r1 = (kb < EE), r2 = (kb + 4 < EE);   // real (non-pad) quads
        #pragma unroll
        for (int t = 0; t < 2; ++t) {
            const int lrow = wv * 32 + t * 16 + l15;
            const int p0 = (2 * l4)     ^ (lrow & 7);
            const int p1 = (2 * l4 + 1) ^ (lrow & 7);
            const f32x4 v0 = *(const f32x4*)&s_doc[buf][lrow * KC + p0 * 4];
            const f32x4 v1 = *(const f32x4*)&s_doc[buf][lrow * KC + p1 * 4];
            if (r1) ssq[t] += v0.x * v0.x + v0.y * v0.y + v0.z * v0.z + v0.w * v0.w;
            if (r2) ssq[t] += v1.x * v1.x + v1.y * v1.y + v1.z * v1.z + v1.w * v1.w;

            short8v bhi, blo;
            #pragma unroll
            for (int j = 0; j < 4; ++j) {
                unsigned short h0 = f2bf(v0[j]);
                unsigned short h1 = f2bf(v1[j]);
                bhi[j]     = (short)h0;
                bhi[j + 4] = (short)h1;
                blo[j]     = (short)f2bf(v0[j] - bf2f(h0));
                blo[j + 4] = (short)f2bf(v1[j] - bf2f(h1));
            }
            acc[0][t] = __builtin_amdgcn_mfma_f32_16x16x32_bf16(ah[0], bhi, acc[0][t], 0, 0, 0);
            acc[0][t] = __builtin_amdgcn_mfma_f32_16x16x32_bf16(ah[0], blo, acc[0][t], 0, 0, 0);
            acc[0][t] = __builtin_amdgcn_mfma_f32_16x16x32_bf16(al[0], bhi, acc[0][t], 0, 0, 0);
            if (nqt > 1) {
                acc[1][t] = __builtin_amdgcn_mfma_f32_16x16x32_bf16(ah[1], bhi, acc[1][t], 0, 0, 0);
                acc[1][t] = __builtin_amdgcn_mfma_f32_16x16x32_bf16(ah[1], blo, acc[1][t], 0, 0, 0);
                acc[1][t] = __builtin_amdgcn_mfma_f32_16x16x32_bf16(al[1], bhi, acc[1][t], 0, 0, 0);
            }
        }
    };

    short8v qAh[2], qAl[2], qBh[2], qBl[2];   // qn reg double-buffer (named, static)
    LOADQ(0, qAh, qAl);
    STAGE(0, 0);

    #pragma unroll
    for (int cc = 0; cc < NCH; cc += 2) {
        // even chunk cc (buffer 0)
        if (cc + 1 < NCH) {
            LOADQ(cc + 1, qBh, qBl);          // issue qn(c+1) BEFORE stage(c+1):
            STAGE(cc + 1, 1);                 // counted wait below leaves both in flight
            if (nqt > 1) asm volatile("s_waitcnt vmcnt(8)" ::: "memory");
            else         asm volatile("s_waitcnt vmcnt(6)" ::: "memory");
        } else {
            asm volatile("s_waitcnt vmcnt(0)" ::: "memory");
        }
        __builtin_amdgcn_s_barrier();
        BODY(cc, 0, qAh, qAl);
        __builtin_amdgcn_s_barrier();

        // odd chunk cc+1 (buffer 1)
        if (cc + 2 < NCH) {
            LOADQ(cc + 2, qAh, qAl);
            STAGE(cc + 2, 0);
            if (nqt > 1) asm volatile("s_waitcnt vmcnt(8)" ::: "memory");
            else         asm volatile("s_waitcnt vmcnt(6)" ::: "memory");
        } else {
            asm volatile("s_waitcnt vmcnt(0)" ::: "memory");
        }
        __builtin_amdgcn_s_barrier();
        BODY(cc + 1, 1, qBh, qBl);
        __builtin_amdgcn_s_barrier();
    }

    // full row-norms: combine the 4 k-window partials (lanes l, l^16, l^32)
    float rinv[2];
    #pragma unroll
    for (int t = 0; t < 2; ++t) {
        float s = ssq[t];
        s += __shfl_xor(s, 16);
        s += __shfl_xor(s, 32);
        rinv[t] = 1.0f / sqrtf(s);        // row (l15) of tile t
    }

    // histogram in LDS, aliasing s_doc (dead after the loop's final barrier)
    int* hist = (int*)&s_doc[0][0];       // [QQ][32]
    for (int s = tid; s < QQ * 32; s += 256) hist[s] = 0;
    __syncthreads();

    // D layout (m89-verified): col = lane&15 (= d in tile), row = (lane>>4)*4 + reg (= q)
    #pragma unroll
    for (int qt = 0; qt < 2; ++qt) {
        #pragma unroll
        for (int r = 0; r < 4; ++r) {
            const int q = qt * 16 + l4 * 4 + r;
            if (q < len) {
                #pragma unroll
                for (int t = 0; t < 2; ++t) {
                    float sim = acc[qt][t][r] * rinv[t];
                    int bin = (int)floorf((sim + 1.0f) * 15.0f);
                    bin = bin < 0 ? 0 : (bin > 29 ? 29 : bin);
                    atomicAdd(&hist[q * 32 + bin], 1);
                }
            }
        }
    }
    __syncthreads();

    for (int s = tid; s < QQ * NB; s += 256) {
        const int q = s / NB, bin = s % NB;
        int tot = hist[q * 32 + bin];
        if (tot) atomicAdd(&ghist[((size_t)b * QQ + q) * NB + bin], tot);
    }
}

// ---------------- final: log1p + FFN + softmax gate + weighted sum ----------------
__global__ __launch_bounds__(64) void drmm_final(const int* __restrict__ ghist,
                                                 const float* __restrict__ glog,
                                                 const float* __restrict__ W1,
                                                 const float* __restrict__ b1,
                                                 const float* __restrict__ W2,
                                                 const float* __restrict__ b2,
                                                 const float* __restrict__ W3,
                                                 const float* __restrict__ b3,
                                                 float* __restrict__ out) {
    const int b = blockIdx.x;
    const int lane = threadIdx.x;         // lanes 0..31 carry q
    float z = 0.f, lg = -1e30f;
    if (lane < QQ) {
        const int* hrow = ghist + ((size_t)b * QQ + lane) * NB;
        float h[NB];
        #pragma unroll
        for (int v = 0; v < NB; ++v) h[v] = log1pf((float)hrow[v]);
        float t1[5];
        #pragma unroll
        for (int u = 0; u < 5; ++u) {
            float s = b1[u];
            #pragma unroll
            for (int v = 0; v < NB; ++v) s += W1[u * NB + v] * h[v];
            t1[u] = tanhf(s);
        }
        float s2 = b2[0];
        #pragma unroll
        for (int u = 0; u < 5; ++u) s2 += W2[u] * t1[u];
        z = tanhf(W3[0] * tanhf(s2) + b3[0]);
        lg = glog[b * QQ + lane];
    }
    float m = lg;
    for (int o = 16; o >= 1; o >>= 1) m = fmaxf(m, __shfl_xor(m, o));
    float e = (lane < QQ) ? expf(lg - m) : 0.f;
    float s = e;
    for (int o = 16; o >= 1; o >>= 1) s += __shfl_xor(s, o);
    float w = z * (e / s);
    for (int o = 16; o >= 1; o >>= 1) w += __shfl_xor(w, o);
    if (lane == 0) out[b] = w;
}

extern "C" void kernel_launch(void* const* d_in, const int* in_sizes, int n_in,
                              void* d_out, int out_size, void* d_ws, size_t ws_size,
                              hipStream_t stream) {
    const float* query = (const float*)d_in[0];
    const float* doc   = (const float*)d_in[1];
    const int*   qlen  = (const int*)d_in[2];
    const float* W1    = (const float*)d_in[3];
    const float* b1    = (const float*)d_in[4];
    const float* W2    = (const float*)d_in[5];
    const float* b2    = (const float*)d_in[6];
    const float* W3    = (const float*)d_in[7];
    const float* b3    = (const float*)d_in[8];
    const float* Wg    = (const float*)d_in[9];
    const float* bg    = (const float*)d_in[10];
    float* out = (float*)d_out;

    unsigned short* qh = (unsigned short*)d_ws;            // [2048][320] bf16 hi
    unsigned short* ql = qh + (size_t)BB * QQ * EPAD;      // [2048][320] bf16 lo
    float* glog = (float*)(ql + (size_t)BB * QQ * EPAD);   // [2048]
    int*   hist = (int*)(glog + BB * QQ);                  // [64][32][30]

    hipLaunchKernelGGL(drmm_prep, dim3(BB * QQ), dim3(64), 0, stream,
                       query, Wg, bg, qh, ql, glog, hist);
    hipLaunchKernelGGL(drmm_main, dim3(BB * NDT), dim3(256), 0, stream,
                       doc, qlen, qh, ql, hist);
    hipLaunchKernelGGL(drmm_final, dim3(BB), dim3(64), 0, stream,
                       hist, glog, W1, b1, W2, b2, W3, b3, out);
}

// Round 11
// 203.248 us; speedup vs baseline: 1.2011x; 1.2011x over previous
//
#include <hip/hip_runtime.h>
#include <math.h>

#define BB 64
#define QQ 32
#define DD 4096
#define EE 300
#define EPAD 320         // qn k-padded with zeros to 320 (10 chunks of 32)
#define NB 30
#define TDB 128          // doc rows per block
#define NDT (DD/TDB)     // 32
#define KC 32            // floats per K-chunk
#define NCH 10

typedef __attribute__((ext_vector_type(8))) short short8v;   // 8 bf16 = 1 MFMA frag
typedef __attribute__((ext_vector_type(4))) float f32x4;

// RNE float->bf16 (bit pattern), and bf16->float
static __device__ __forceinline__ unsigned short f2bf(float x) {
    unsigned int u = __builtin_bit_cast(unsigned int, x);
    u = (u + 0x7FFFu + ((u >> 16) & 1u)) >> 16;
    return (unsigned short)u;
}
static __device__ __forceinline__ float bf2f(unsigned short h) {
    return __builtin_bit_cast(float, (unsigned int)h << 16);
}

// ---------------- prep: normalize query, split to bf16 hi/lo, gate logits, zero hist ----
__global__ __launch_bounds__(64) void drmm_prep(const float* __restrict__ query,
                                                const float* __restrict__ Wg,
                                                const float* __restrict__ bg,
                                                unsigned short* __restrict__ qh,
                                                unsigned short* __restrict__ ql,
                                                float* __restrict__ glog,
                                                int* __restrict__ ghist) {
    const int row  = blockIdx.x;          // b*32+q
    const int lane = threadIdx.x;         // 0..63
    if (lane < NB) ghist[(size_t)row * NB + lane] = 0;   // replaces memset dispatch
    const float* src = query + (size_t)row * EE;
    float ss = 0.f;
    for (int e = lane; e < EE; e += 64) { float x = src[e]; ss += x * x; }
    for (int o = 1; o < 64; o <<= 1) ss += __shfl_xor(ss, o);
    const float inv = 1.0f / sqrtf(ss);
    float gd = 0.f;
    #pragma unroll
    for (int it = 0; it < 5; ++it) {      // 5*64 = 320 = EPAD
        int e = it * 64 + lane;
        float x = (e < EE) ? src[e] * inv : 0.f;
        unsigned short h = f2bf(x);
        float lo = x - bf2f(h);
        qh[(size_t)row * EPAD + e] = h;
        ql[(size_t)row * EPAD + e] = f2bf(lo);
        if (e < EE) gd += x * Wg[e];
    }
    for (int o = 1; o < 64; o <<= 1) gd += __shfl_xor(gd, o);
    if (lane == 0) glog[row] = gd + bg[0];
}

// ---------------- main: LDS-staged doc + direct-global qn MFMA + histogram ----------------
// 256 threads = 4 waves; wave wv owns doc rows [wv*32,+32) of the block's 128-row
// tile (2 MFMA tiles of 16). Per 32-float chunk: doc staged via 4 global_load_lds
// per thread (XOR-swizzled source, linear dest), qn A-fragments loaded DIRECTLY
// global->VGPR (L2-hot), register-double-buffered across even/odd bodies.
// Counted vmcnt(8/6); 2 barriers/chunk. LDS 32 KB; __launch_bounds__(256,4)
// (NOT 5 — R10 post-mortem: 5 waves/EU forces VGPR cap 48 -> 372 MB spill).
__global__ __launch_bounds__(256, 4) void drmm_main(const float* __restrict__ doc,
                                                    const int* __restrict__ qlen,
                                                    const unsigned short* __restrict__ qh,
                                                    const unsigned short* __restrict__ ql,
                                                    int* __restrict__ ghist) {
    __shared__ __align__(16) float s_doc[2][TDB * KC];   // 2 x 16 KB (hist aliases later)

    const int b   = blockIdx.x >> 5;
    const int dt  = blockIdx.x & 31;
    const int len = __builtin_amdgcn_readfirstlane(qlen[b]);
    if (len == 0) return;                 // hist stays zero (prep zeroed ghist)

    const int tid = threadIdx.x;
    const int wv  = tid >> 6;             // wave id (uniform)
    const int l15 = tid & 15;             // fragment row index
    const int l4  = (tid >> 4) & 3;       // k-window (0..3), 8 floats each
    const int nqt = (len > 16) ? 2 : 1;   // q-tiles needed (scalar)

    const float* docb = doc + ((size_t)b * DD + dt * TDB) * EE;
    const unsigned short* qhb = qh + ((size_t)b * QQ + l15) * EPAD + l4 * 8;
    const unsigned short* qlb = ql + ((size_t)b * QQ + l15) * EPAD + l4 * 8;

    // stage doc chunk c into buffer buf: 4 global_load_lds per thread.
    // 1024 16B-slots; slot S=i*256+tid -> row r=S>>3, phys slot p=S&7 holds
    // logical slot p^(r&7) (inverse-swizzled source, linear LDS dest).
    auto STAGE = [&](int c, int buf) {
        #pragma unroll
        for (int i = 0; i < 4; ++i) {
            int S  = i * 256 + tid;
            int r  = S >> 3;
            int lg = (S & 7) ^ (r & 7);
            int kk = c * KC + 4 * lg;
            if (kk >= EE) kk = 0;         // pad slot: redirect in-bounds (qn pad=0)
            __builtin_amdgcn_global_load_lds(
                (const __attribute__((address_space(1))) void*)(docb + (size_t)r * EE + kk),
                (__attribute__((address_space(3))) void*)&s_doc[buf][(i * 256 + wv * 64) * 4],
                16, 0, 0);
        }
    };
    // load qn A-fragments for chunk c (direct global, L2-hot)
    auto LOADQ = [&](int c, short8v (&ah)[2], short8v (&al)[2]) {
        ah[0] = *(const short8v*)(qhb + c * KC);
        al[0] = *(const short8v*)(qlb + c * KC);
        if (nqt > 1) {
            ah[1] = *(const short8v*)(qhb + 16 * EPAD + c * KC);
            al[1] = *(const short8v*)(qlb + 16 * EPAD + c * KC);
        }
    };

    f32x4 acc[2][2];
    #pragma unroll
    for (int qt = 0; qt < 2; ++qt)
        #pragma unroll
        for (int t = 0; t < 2; ++t) acc[qt][t] = (f32x4){0.f, 0.f, 0.f, 0.f};
    float ssq[2] = {0.f, 0.f};

    // compute chunk c from buffer buf with pre-loaded qn fragments
    auto BODY = [&](int c, int buf, const short8v (&ah)[2], const short8v (&al)[2]) {
        const int kb = c * KC + l4 * 8;
        const bool r1 = (kb < EE), r2 = (kb + 4 < EE);   // real (non-pad) quads
        #pragma unroll
        for (int t = 0; t < 2; ++t) {
            const int lrow = wv * 32 + t * 16 + l15;
            const int p0 = (2 * l4)     ^ (lrow & 7);
            const int p1 = (2 * l4 + 1) ^ (lrow & 7);
            const f32x4 v0 = *(const f32x4*)&s_doc[buf][lrow * KC + p0 * 4];
            const f32x4 v1 = *(const f32x4*)&s_doc[buf][lrow * KC + p1 * 4];
            if (r1) ssq[t] += v0.x * v0.x + v0.y * v0.y + v0.z * v0.z + v0.w * v0.w;
            if (r2) ssq[t] += v1.x * v1.x + v1.y * v1.y + v1.z * v1.z + v1.w * v1.w;

            short8v bhi, blo;
            #pragma unroll
            for (int j = 0; j < 4; ++j) {
                unsigned short h0 = f2bf(v0[j]);
                unsigned short h1 = f2bf(v1[j]);
                bhi[j]     = (short)h0;
                bhi[j + 4] = (short)h1;
                blo[j]     = (short)f2bf(v0[j] - bf2f(h0));
                blo[j + 4] = (short)f2bf(v1[j] - bf2f(h1));
            }
            acc[0][t] = __builtin_amdgcn_mfma_f32_16x16x32_bf16(ah[0], bhi, acc[0][t], 0, 0, 0);
            acc[0][t] = __builtin_amdgcn_mfma_f32_16x16x32_bf16(ah[0], blo, acc[0][t], 0, 0, 0);
            acc[0][t] = __builtin_amdgcn_mfma_f32_16x16x32_bf16(al[0], bhi, acc[0][t], 0, 0, 0);
            if (nqt > 1) {
                acc[1][t] = __builtin_amdgcn_mfma_f32_16x16x32_bf16(ah[1], bhi, acc[1][t], 0, 0, 0);
                acc[1][t] = __builtin_amdgcn_mfma_f32_16x16x32_bf16(ah[1], blo, acc[1][t], 0, 0, 0);
                acc[1][t] = __builtin_amdgcn_mfma_f32_16x16x32_bf16(al[1], bhi, acc[1][t], 0, 0, 0);
            }
        }
    };

    short8v qAh[2], qAl[2], qBh[2], qBl[2];   // qn reg double-buffer (named, static)
    LOADQ(0, qAh, qAl);
    STAGE(0, 0);

    #pragma unroll
    for (int cc = 0; cc < NCH; cc += 2) {
        // even chunk cc (buffer 0)
        if (cc + 1 < NCH) {
            LOADQ(cc + 1, qBh, qBl);          // issue qn(c+1) BEFORE stage(c+1):
            STAGE(cc + 1, 1);                 // counted wait leaves both in flight
            if (nqt > 1) asm volatile("s_waitcnt vmcnt(8)" ::: "memory");
            else         asm volatile("s_waitcnt vmcnt(6)" ::: "memory");
        } else {
            asm volatile("s_waitcnt vmcnt(0)" ::: "memory");
        }
        __builtin_amdgcn_s_barrier();
        BODY(cc, 0, qAh, qAl);
        __builtin_amdgcn_s_barrier();

        // odd chunk cc+1 (buffer 1)
        if (cc + 2 < NCH) {
            LOADQ(cc + 2, qAh, qAl);
            STAGE(cc + 2, 0);
            if (nqt > 1) asm volatile("s_waitcnt vmcnt(8)" ::: "memory");
            else         asm volatile("s_waitcnt vmcnt(6)" ::: "memory");
        } else {
            asm volatile("s_waitcnt vmcnt(0)" ::: "memory");
        }
        __builtin_amdgcn_s_barrier();
        BODY(cc + 1, 1, qBh, qBl);
        __builtin_amdgcn_s_barrier();
    }

    // full row-norms: combine the 4 k-window partials (lanes l, l^16, l^32)
    float rinv[2];
    #pragma unroll
    for (int t = 0; t < 2; ++t) {
        float s = ssq[t];
        s += __shfl_xor(s, 16);
        s += __shfl_xor(s, 32);
        rinv[t] = 1.0f / sqrtf(s);        // row (l15) of tile t
    }

    // histogram in LDS, aliasing s_doc (dead after the loop's final barrier)
    int* hist = (int*)&s_doc[0][0];       // [QQ][32]
    for (int s = tid; s < QQ * 32; s += 256) hist[s] = 0;
    __syncthreads();

    // D layout (m89-verified): col = lane&15 (= d in tile), row = (lane>>4)*4 + reg (= q)
    #pragma unroll
    for (int qt = 0; qt < 2; ++qt) {
        #pragma unroll
        for (int r = 0; r < 4; ++r) {
            const int q = qt * 16 + l4 * 4 + r;
            if (q < len) {
                #pragma unroll
                for (int t = 0; t < 2; ++t) {
                    float sim = acc[qt][t][r] * rinv[t];
                    int bin = (int)floorf((sim + 1.0f) * 15.0f);
                    bin = bin < 0 ? 0 : (bin > 29 ? 29 : bin);
                    atomicAdd(&hist[q * 32 + bin], 1);
                }
            }
        }
    }
    __syncthreads();

    for (int s = tid; s < QQ * NB; s += 256) {
        const int q = s / NB, bin = s % NB;
        int tot = hist[q * 32 + bin];
        if (tot) atomicAdd(&ghist[((size_t)b * QQ + q) * NB + bin], tot);
    }
}

// ---------------- final: log1p + FFN + softmax gate + weighted sum ----------------
__global__ __launch_bounds__(64) void drmm_final(const int* __restrict__ ghist,
                                                 const float* __restrict__ glog,
                                                 const float* __restrict__ W1,
                                                 const float* __restrict__ b1,
                                                 const float* __restrict__ W2,
                                                 const float* __restrict__ b2,
                                                 const float* __restrict__ W3,
                                                 const float* __restrict__ b3,
                                                 float* __restrict__ out) {
    const int b = blockIdx.x;
    const int lane = threadIdx.x;         // lanes 0..31 carry q
    float z = 0.f, lg = -1e30f;
    if (lane < QQ) {
        const int* hrow = ghist + ((size_t)b * QQ + lane) * NB;
        float h[NB];
        #pragma unroll
        for (int v = 0; v < NB; ++v) h[v] = log1pf((float)hrow[v]);
        float t1[5];
        #pragma unroll
        for (int u = 0; u < 5; ++u) {
            float s = b1[u];
            #pragma unroll
            for (int v = 0; v < NB; ++v) s += W1[u * NB + v] * h[v];
            t1[u] = tanhf(s);
        }
        float s2 = b2[0];
        #pragma unroll
        for (int u = 0; u < 5; ++u) s2 += W2[u] * t1[u];
        z = tanhf(W3[0] * tanhf(s2) + b3[0]);
        lg = glog[b * QQ + lane];
    }
    float m = lg;
    for (int o = 16; o >= 1; o >>= 1) m = fmaxf(m, __shfl_xor(m, o));
    float e = (lane < QQ) ? expf(lg - m) : 0.f;
    float s = e;
    for (int o = 16; o >= 1; o >>= 1) s += __shfl_xor(s, o);
    float w = z * (e / s);
    for (int o = 16; o >= 1; o >>= 1) w += __shfl_xor(w, o);
    if (lane == 0) out[b] = w;
}

extern "C" void kernel_launch(void* const* d_in, const int* in_sizes, int n_in,
                              void* d_out, int out_size, void* d_ws, size_t ws_size,
                              hipStream_t stream) {
    const float* query = (const float*)d_in[0];
    const float* doc   = (const float*)d_in[1];
    const int*   qlen  = (const int*)d_in[2];
    const float* W1    = (const float*)d_in[3];
    const float* b1    = (const float*)d_in[4];
    const float* W2    = (const float*)d_in[5];
    const float* b2    = (const float*)d_in[6];
    const float* W3    = (const float*)d_in[7];
    const float* b3    = (const float*)d_in[8];
    const float* Wg    = (const float*)d_in[9];
    const float* bg    = (const float*)d_in[10];
    float* out = (float*)d_out;

    unsigned short* qh = (unsigned short*)d_ws;            // [2048][320] bf16 hi
    unsigned short* ql = qh + (size_t)BB * QQ * EPAD;      // [2048][320] bf16 lo
    float* glog = (float*)(ql + (size_t)BB * QQ * EPAD);   // [2048]
    int*   hist = (int*)(glog + BB * QQ);                  // [64][32][30]

    hipLaunchKernelGGL(drmm_prep, dim3(BB * QQ), dim3(64), 0, stream,
                       query, Wg, bg, qh, ql, glog, hist);
    hipLaunchKernelGGL(drmm_main, dim3(BB * NDT), dim3(256), 0, stream,
                       doc, qlen, qh, ql, hist);
    hipLaunchKernelGGL(drmm_final, dim3(BB), dim3(64), 0, stream,
                       hist, glog, W1, b1, W2, b2, W3, b3, out);
}

// Round 12
// 128.216 us; speedup vs baseline: 1.9039x; 1.5852x over previous
//
#include <hip/hip_runtime.h>
#include <math.h>

#define BB 64
#define QQ 32
#define DD 4096
#define EE 300
#define EPAD 320         // qn k-padded with zeros to 320 (5 chunks of 64)
#define NB 30
#define TDB 64           // doc rows per block (one 16-row MFMA tile per wave)
#define NDT (DD/TDB)     // 64
#define KC 64            // floats per K-chunk (256 B bursts per row)
#define NCH 5

typedef __attribute__((ext_vector_type(8))) short short8v;   // 8 bf16 = 1 MFMA frag
typedef __attribute__((ext_vector_type(4))) float f32x4;

// RNE float->bf16 (bit pattern), and bf16->float
static __device__ __forceinline__ unsigned short f2bf(float x) {
    unsigned int u = __builtin_bit_cast(unsigned int, x);
    u = (u + 0x7FFFu + ((u >> 16) & 1u)) >> 16;
    return (unsigned short)u;
}
static __device__ __forceinline__ float bf2f(unsigned short h) {
    return __builtin_bit_cast(float, (unsigned int)h << 16);
}

// ---------------- prep: normalize query, split to bf16 hi/lo, gate logits, zero hist ----
__global__ __launch_bounds__(64) void drmm_prep(const float* __restrict__ query,
                                                const float* __restrict__ Wg,
                                                const float* __restrict__ bg,
                                                unsigned short* __restrict__ qh,
                                                unsigned short* __restrict__ ql,
                                                float* __restrict__ glog,
                                                int* __restrict__ ghist) {
    const int row  = blockIdx.x;          // b*32+q
    const int lane = threadIdx.x;         // 0..63
    if (lane < NB) ghist[(size_t)row * NB + lane] = 0;   // replaces memset dispatch
    const float* src = query + (size_t)row * EE;
    float ss = 0.f;
    for (int e = lane; e < EE; e += 64) { float x = src[e]; ss += x * x; }
    for (int o = 1; o < 64; o <<= 1) ss += __shfl_xor(ss, o);
    const float inv = 1.0f / sqrtf(ss);
    float gd = 0.f;
    #pragma unroll
    for (int it = 0; it < 5; ++it) {      // 5*64 = 320 = EPAD
        int e = it * 64 + lane;
        float x = (e < EE) ? src[e] * inv : 0.f;
        unsigned short h = f2bf(x);
        float lo = x - bf2f(h);
        qh[(size_t)row * EPAD + e] = h;
        ql[(size_t)row * EPAD + e] = f2bf(lo);
        if (e < EE) gd += x * Wg[e];
    }
    for (int o = 1; o < 64; o <<= 1) gd += __shfl_xor(gd, o);
    if (lane == 0) glog[row] = gd + bg[0];
}

// ---------------- main: LDS-staged doc (256B bursts) + JIT-global qn MFMA + histogram ----
// 256 threads = 4 waves; wave wv owns ONE 16-row tile (rows dt*64 + wv*16 + l15).
// Per 64-float chunk: doc staged via 4 global_load_lds/thread (16 slots/row,
// swizzle p = quad ^ (row&15), inverse-swizzled source, linear dest); qn A-frags
// loaded just-in-time from global (L2-hot, live one iteration only — the R11
// double-buffer overflowed the arch-VGPR half and spilled 270 MB). Counted
// vmcnt(4): LOADQ(c) issued BEFORE STAGE(c+1), so the wait drains qn(c)+stage(c)
// and leaves exactly stage(c+1) in flight. 10 barriers/block. LDS 32 KB.
__global__ __launch_bounds__(256, 4) void drmm_main(const float* __restrict__ doc,
                                                    const int* __restrict__ qlen,
                                                    const unsigned short* __restrict__ qh,
                                                    const unsigned short* __restrict__ ql,
                                                    int* __restrict__ ghist) {
    __shared__ __align__(16) float s_doc[2][TDB * KC];   // 2 x 16 KB (hist aliases later)

    const int b   = blockIdx.x >> 6;
    const int dt  = blockIdx.x & 63;
    const int len = __builtin_amdgcn_readfirstlane(qlen[b]);
    if (len == 0) return;                 // hist stays zero (prep zeroed ghist)

    const int tid = threadIdx.x;
    const int wv  = tid >> 6;             // wave id (uniform)
    const int l15 = tid & 15;             // fragment row / doc row within tile
    const int l4  = (tid >> 4) & 3;       // k-subwindow (0..3), 8 floats each
    const int nqt = (len > 16) ? 2 : 1;   // q-tiles needed (scalar)

    const float* docb = doc + ((size_t)b * DD + dt * TDB) * EE;
    const unsigned short* qhb = qh + ((size_t)b * QQ + l15) * EPAD + l4 * 8;
    const unsigned short* qlb = ql + ((size_t)b * QQ + l15) * EPAD + l4 * 8;

    // stage doc chunk c into buffer buf: 4 global_load_lds per thread.
    // 1024 16B-slots; slot S=i*256+tid -> row r=S>>4, phys quad p=S&15 holds
    // logical quad p^(r&15) (inverse-swizzled source, linear LDS dest).
    auto STAGE = [&](int c, int buf) {
        #pragma unroll
        for (int i = 0; i < 4; ++i) {
            int S  = i * 256 + tid;
            int r  = S >> 4;
            int lq = (S & 15) ^ (r & 15);
            int kk = c * KC + 4 * lq;
            if (kk >= EE) kk = 0;         // pad quad: redirect in-bounds (qn pad=0)
            __builtin_amdgcn_global_load_lds(
                (const __attribute__((address_space(1))) void*)(docb + (size_t)r * EE + kk),
                (__attribute__((address_space(3))) void*)&s_doc[buf][(i * 256 + wv * 64) * 4],
                16, 0, 0);
        }
    };

    f32x4 acc[2];                          // [qt], one tile per wave
    acc[0] = (f32x4){0.f, 0.f, 0.f, 0.f};
    acc[1] = (f32x4){0.f, 0.f, 0.f, 0.f};
    float ssq = 0.f;                       // row l15 partial (k-windows of this lane)

    STAGE(0, 0);

    #pragma unroll
    for (int c = 0; c < NCH; ++c) {
        const int cur = c & 1;
        // qn A-fragments for chunk c (JIT, L2-hot, live this iteration only):
        // [qt][half]; issued BEFORE next stage so vmcnt(4) drains them.
        short8v ah00 = *(const short8v*)(qhb + c * KC);
        short8v al00 = *(const short8v*)(qlb + c * KC);
        short8v ah01 = *(const short8v*)(qhb + c * KC + 32);
        short8v al01 = *(const short8v*)(qlb + c * KC + 32);
        short8v ah10 = {}, al10 = {}, ah11 = {}, al11 = {};
        if (nqt > 1) {
            ah10 = *(const short8v*)(qhb + 16 * EPAD + c * KC);
            al10 = *(const short8v*)(qlb + 16 * EPAD + c * KC);
            ah11 = *(const short8v*)(qhb + 16 * EPAD + c * KC + 32);
            al11 = *(const short8v*)(qlb + 16 * EPAD + c * KC + 32);
        }
        if (c + 1 < NCH) {
            STAGE(c + 1, cur ^ 1);
            asm volatile("s_waitcnt vmcnt(4)" ::: "memory");
        } else {
            asm volatile("s_waitcnt vmcnt(0)" ::: "memory");
        }
        __builtin_amdgcn_s_barrier();

        const int rowb = (wv * 16 + l15) * KC;   // this lane's doc row in LDS
        #pragma unroll
        for (int h = 0; h < 2; ++h) {
            const int q0 = h * 8 + 2 * l4;       // logical quads of this fragment
            const int p0 = q0 ^ l15;             // swizzle key = row&15 = l15
            const int p1 = (q0 + 1) ^ l15;
            const f32x4 v0 = *(const f32x4*)&s_doc[cur][rowb + 4 * p0];
            const f32x4 v1 = *(const f32x4*)&s_doc[cur][rowb + 4 * p1];
            const int kb = c * KC + h * 32 + l4 * 8;
            if (kb < EE)     ssq += v0.x * v0.x + v0.y * v0.y + v0.z * v0.z + v0.w * v0.w;
            if (kb + 4 < EE) ssq += v1.x * v1.x + v1.y * v1.y + v1.z * v1.z + v1.w * v1.w;

            short8v bhi, blo;
            #pragma unroll
            for (int j = 0; j < 4; ++j) {
                unsigned short h0 = f2bf(v0[j]);
                unsigned short h1 = f2bf(v1[j]);
                bhi[j]     = (short)h0;
                bhi[j + 4] = (short)h1;
                blo[j]     = (short)f2bf(v0[j] - bf2f(h0));
                blo[j + 4] = (short)f2bf(v1[j] - bf2f(h1));
            }
            const short8v ah0 = h ? ah01 : ah00, al0 = h ? al01 : al00;
            acc[0] = __builtin_amdgcn_mfma_f32_16x16x32_bf16(ah0, bhi, acc[0], 0, 0, 0);
            acc[0] = __builtin_amdgcn_mfma_f32_16x16x32_bf16(ah0, blo, acc[0], 0, 0, 0);
            acc[0] = __builtin_amdgcn_mfma_f32_16x16x32_bf16(al0, bhi, acc[0], 0, 0, 0);
            if (nqt > 1) {
                const short8v ah1 = h ? ah11 : ah10, al1 = h ? al11 : al10;
                acc[1] = __builtin_amdgcn_mfma_f32_16x16x32_bf16(ah1, bhi, acc[1], 0, 0, 0);
                acc[1] = __builtin_amdgcn_mfma_f32_16x16x32_bf16(ah1, blo, acc[1], 0, 0, 0);
                acc[1] = __builtin_amdgcn_mfma_f32_16x16x32_bf16(al1, bhi, acc[1], 0, 0, 0);
            }
        }
        __builtin_amdgcn_s_barrier();     // all reads done before buffer re-staged
    }

    // full row-norm for row l15: combine 4 k-subwindow partials (lanes l, l^16, l^32)
    float s = ssq;
    s += __shfl_xor(s, 16);
    s += __shfl_xor(s, 32);
    const float rinv = 1.0f / sqrtf(s);

    // histogram in LDS, aliasing s_doc (dead after the loop's final barrier)
    int* hist = (int*)&s_doc[0][0];       // [QQ][32]
    for (int i = tid; i < QQ * 32; i += 256) hist[i] = 0;
    __syncthreads();

    // D layout (m89-verified): col = lane&15 (= doc row in tile), row = (lane>>4)*4 + reg (= q)
    #pragma unroll
    for (int qt = 0; qt < 2; ++qt) {
        #pragma unroll
        for (int r = 0; r < 4; ++r) {
            const int q = qt * 16 + l4 * 4 + r;
            if (q < len) {
                float sim = acc[qt][r] * rinv;
                int bin = (int)floorf((sim + 1.0f) * 15.0f);
                bin = bin < 0 ? 0 : (bin > 29 ? 29 : bin);
                atomicAdd(&hist[q * 32 + bin], 1);
            }
        }
    }
    __syncthreads();

    for (int i = tid; i < QQ * NB; i += 256) {
        const int q = i / NB, bin = i % NB;
        int tot = hist[q * 32 + bin];
        if (tot) atomicAdd(&ghist[((size_t)b * QQ + q) * NB + bin], tot);
    }
}

// ---------------- final: log1p + FFN + softmax gate + weighted sum ----------------
__global__ __launch_bounds__(64) void drmm_final(const int* __restrict__ ghist,
                                                 const float* __restrict__ glog,
                                                 const float* __restrict__ W1,
                                                 const float* __restrict__ b1,
                                                 const float* __restrict__ W2,
                                                 const float* __restrict__ b2,
                                                 const float* __restrict__ W3,
                                                 const float* __restrict__ b3,
                                                 float* __restrict__ out) {
    const int b = blockIdx.x;
    const int lane = threadIdx.x;         // lanes 0..31 carry q
    float z = 0.f, lg = -1e30f;
    if (lane < QQ) {
        const int* hrow = ghist + ((size_t)b * QQ + lane) * NB;
        float h[NB];
        #pragma unroll
        for (int v = 0; v < NB; ++v) h[v] = log1pf((float)hrow[v]);
        float t1[5];
        #pragma unroll
        for (int u = 0; u < 5; ++u) {
            float s = b1[u];
            #pragma unroll
            for (int v = 0; v < NB; ++v) s += W1[u * NB + v] * h[v];
            t1[u] = tanhf(s);
        }
        float s2 = b2[0];
        #pragma unroll
        for (int u = 0; u < 5; ++u) s2 += W2[u] * t1[u];
        z = tanhf(W3[0] * tanhf(s2) + b3[0]);
        lg = glog[b * QQ + lane];
    }
    float m = lg;
    for (int o = 16; o >= 1; o >>= 1) m = fmaxf(m, __shfl_xor(m, o));
    float e = (lane < QQ) ? expf(lg - m) : 0.f;
    float s = e;
    for (int o = 16; o >= 1; o >>= 1) s += __shfl_xor(s, o);
    float w = z * (e / s);
    for (int o = 16; o >= 1; o >>= 1) w += __shfl_xor(w, o);
    if (lane == 0) out[b] = w;
}

extern "C" void kernel_launch(void* const* d_in, const int* in_sizes, int n_in,
                              void* d_out, int out_size, void* d_ws, size_t ws_size,
                              hipStream_t stream) {
    const float* query = (const float*)d_in[0];
    const float* doc   = (const float*)d_in[1];
    const int*   qlen  = (const int*)d_in[2];
    const float* W1    = (const float*)d_in[3];
    const float* b1    = (const float*)d_in[4];
    const float* W2    = (const float*)d_in[5];
    const float* b2    = (const float*)d_in[6];
    const float* W3    = (const float*)d_in[7];
    const float* b3    = (const float*)d_in[8];
    const float* Wg    = (const float*)d_in[9];
    const float* bg    = (const float*)d_in[10];
    float* out = (float*)d_out;

    unsigned short* qh = (unsigned short*)d_ws;            // [2048][320] bf16 hi
    unsigned short* ql = qh + (size_t)BB * QQ * EPAD;      // [2048][320] bf16 lo
    float* glog = (float*)(ql + (size_t)BB * QQ * EPAD);   // [2048]
    int*   hist = (int*)(glog + BB * QQ);                  // [64][32][30]

    hipLaunchKernelGGL(drmm_prep, dim3(BB * QQ), dim3(64), 0, stream,
                       query, Wg, bg, qh, ql, glog, hist);
    hipLaunchKernelGGL(drmm_main, dim3(BB * NDT), dim3(256), 0, stream,
                       doc, qlen, qh, ql, hist);
    hipLaunchKernelGGL(drmm_final, dim3(BB), dim3(64), 0, stream,
                       hist, glog, W1, b1, W2, b2, W3, b3, out);
}

// Round 13
// 94.874 us; speedup vs baseline: 2.5730x; 1.3514x over previous
//
#include <hip/hip_runtime.h>
#include <math.h>

#define BB 64
#define QQ 32
#define DD 4096
#define EE 300
#define EPAD 320         // qn k-padded with zeros to 320 (10 chunks of 32)
#define NB 30
#define TDB 128          // doc rows per block
#define NDT (DD/TDB)     // 32
#define KC 32            // floats per K-chunk
#define NCH 10

typedef __attribute__((ext_vector_type(8))) short short8v;   // 8 bf16 = 1 MFMA frag
typedef __attribute__((ext_vector_type(4))) float f32x4;

// RNE float->bf16 (bit pattern), and bf16->float
static __device__ __forceinline__ unsigned short f2bf(float x) {
    unsigned int u = __builtin_bit_cast(unsigned int, x);
    u = (u + 0x7FFFu + ((u >> 16) & 1u)) >> 16;
    return (unsigned short)u;
}
static __device__ __forceinline__ float bf2f(unsigned short h) {
    return __builtin_bit_cast(float, (unsigned int)h << 16);
}

// ---------------- prep: normalize query, split to bf16 hi/lo, gate logits, zero hist ----
__global__ __launch_bounds__(64) void drmm_prep(const float* __restrict__ query,
                                                const float* __restrict__ Wg,
                                                const float* __restrict__ bg,
                                                unsigned short* __restrict__ qh,
                                                unsigned short* __restrict__ ql,
                                                float* __restrict__ glog,
                                                int* __restrict__ ghist) {
    const int row  = blockIdx.x;          // b*32+q
    const int lane = threadIdx.x;         // 0..63
    if (lane < NB) ghist[(size_t)row * NB + lane] = 0;   // replaces memset dispatch
    const float* src = query + (size_t)row * EE;
    float ss = 0.f;
    for (int e = lane; e < EE; e += 64) { float x = src[e]; ss += x * x; }
    for (int o = 1; o < 64; o <<= 1) ss += __shfl_xor(ss, o);
    const float inv = 1.0f / sqrtf(ss);
    float gd = 0.f;
    #pragma unroll
    for (int it = 0; it < 5; ++it) {      // 5*64 = 320 = EPAD
        int e = it * 64 + lane;
        float x = (e < EE) ? src[e] * inv : 0.f;
        unsigned short h = f2bf(x);
        float lo = x - bf2f(h);
        qh[(size_t)row * EPAD + e] = h;
        ql[(size_t)row * EPAD + e] = f2bf(lo);
        if (e < EE) gd += x * Wg[e];
    }
    for (int o = 1; o < 64; o <<= 1) gd += __shfl_xor(gd, o);
    if (lane == 0) glog[row] = gd + bg[0];
}

// ---------------- main: LDS-staged MFMA interaction + histogram (R9 champion) ----------
// 256 threads = 4 waves; wave wv owns doc rows [wv*32, wv*32+32) of the block's
// 128-row tile as 2 MFMA tiles of 16. Per 32-float chunk: doc (16 KB, swizzled
// slots) + qn hi/lo chunks (4 KB) staged via global_load_lds, double-buffered,
// counted vmcnt(5) (5 loads/thread/chunk), 2 barriers/chunk.
// LDS 40,960 B -> 4 blocks/CU; in-flight ~80 KB/CU. Hist aliases s_doc after
// the loop. NOTE: this exact point is a register/LDS/occupancy sweet spot —
// R10 (waves/EU=5), R11 (qn reg-dbuf), R12 (KC=64/TDB=64) all regressed.
__global__ __launch_bounds__(256, 4) void drmm_main(const float* __restrict__ doc,
                                                    const int* __restrict__ qlen,
                                                    const unsigned short* __restrict__ qh,
                                                    const unsigned short* __restrict__ ql,
                                                    int* __restrict__ ghist) {
    __shared__ __align__(16) float s_doc[2][TDB * KC];          // 2 x 16 KB
    __shared__ __align__(16) unsigned short s_qh[2][QQ * KC];   // 2 x 2 KB
    __shared__ __align__(16) unsigned short s_ql[2][QQ * KC];   // 2 x 2 KB

    const int b   = blockIdx.x >> 5;
    const int dt  = blockIdx.x & 31;
    const int len = __builtin_amdgcn_readfirstlane(qlen[b]);
    if (len == 0) return;                 // hist stays zero (prep zeroed ghist)

    const int tid = threadIdx.x;
    const int wv  = tid >> 6;             // wave id (uniform)
    const int td  = tid & 63;
    const int l15 = tid & 15;             // fragment row index
    const int l4  = (tid >> 4) & 3;       // k-window (0..3), 8 floats each
    const int nqt = (len > 16) ? 2 : 1;   // q-tiles needed (scalar)

    const float* docb = doc + ((size_t)b * DD + dt * TDB) * EE;
    const unsigned short* qhb = qh + (size_t)b * QQ * EPAD;
    const unsigned short* qlb = ql + (size_t)b * QQ * EPAD;

    // stage chunk c into buffer buf: 4 doc + 1 qn global_load_lds per thread.
    // doc: 1024 16B-slots; slot S=i*256+tid -> row r=S>>3, phys slot p=S&7
    //      holds logical slot p^(r&7) (inverse-swizzled source, linear dest).
    // qn:  waves 0,1 stage qh's 128 slots; waves 2,3 stage ql's; slot s ->
    //      q=s>>2, phys p=s&3 holds logical p^(q&3) (8 bf16 per slot).
    auto STAGE = [&](int c, int buf) {
        #pragma unroll
        for (int i = 0; i < 4; ++i) {
            int S  = i * 256 + tid;
            int r  = S >> 3;
            int lg = (S & 7) ^ (r & 7);
            int kk = c * KC + 4 * lg;
            if (kk >= EE) kk = 0;         // pad slot: redirect in-bounds (qn pad=0)
            __builtin_amdgcn_global_load_lds(
                (const __attribute__((address_space(1))) void*)(docb + (size_t)r * EE + kk),
                (__attribute__((address_space(3))) void*)&s_doc[buf][(i * 256 + wv * 64) * 4],
                16, 0, 0);
        }
        if (wv < 2) {
            int s  = wv * 64 + td;        // qh slot
            int q  = s >> 2;
            int lg = (s & 3) ^ (q & 3);
            __builtin_amdgcn_global_load_lds(
                (const __attribute__((address_space(1))) void*)
                    (qhb + (size_t)q * EPAD + c * KC + 8 * lg),
                (__attribute__((address_space(3))) void*)&s_qh[buf][wv * 512],
                16, 0, 0);
        } else {
            int s  = (wv - 2) * 64 + td;  // ql slot
            int q  = s >> 2;
            int lg = (s & 3) ^ (q & 3);
            __builtin_amdgcn_global_load_lds(
                (const __attribute__((address_space(1))) void*)
                    (qlb + (size_t)q * EPAD + c * KC + 8 * lg),
                (__attribute__((address_space(3))) void*)&s_ql[buf][(wv - 2) * 512],
                16, 0, 0);
        }
    };

    STAGE(0, 0);

    f32x4 acc[2][2];
    #pragma unroll
    for (int qt = 0; qt < 2; ++qt)
        #pragma unroll
        for (int t = 0; t < 2; ++t) acc[qt][t] = (f32x4){0.f, 0.f, 0.f, 0.f};
    float ssq[2] = {0.f, 0.f};

    int cur = 0;
    for (int c = 0; c < NCH; ++c) {
        if (c + 1 < NCH) {
            STAGE(c + 1, cur ^ 1);
            asm volatile("s_waitcnt vmcnt(5)" ::: "memory");
        } else {
            asm volatile("s_waitcnt vmcnt(0)" ::: "memory");
        }
        __builtin_amdgcn_s_barrier();

        // A fragments (qn hi/lo) for this chunk: logical slot l4, phys l4^(q&3)
        short8v ah[2], al[2];
        #pragma unroll
        for (int qt = 0; qt < 2; ++qt) {
            if (qt < nqt) {
                const int qrow = qt * 16 + l15;
                const int p = l4 ^ (qrow & 3);
                ah[qt] = *(const short8v*)&s_qh[cur][qrow * KC + p * 8];
                al[qt] = *(const short8v*)&s_ql[cur][qrow * KC + p * 8];
            }
        }

        const int kb = c * KC + l4 * 8;
        const bool r1 = (kb < EE), r2 = (kb + 4 < EE);   // real (non-pad) quads

        #pragma unroll
        for (int t = 0; t < 2; ++t) {
            const int lrow = wv * 32 + t * 16 + l15;
            const int p0 = (2 * l4)     ^ (lrow & 7);
            const int p1 = (2 * l4 + 1) ^ (lrow & 7);
            const f32x4 v0 = *(const f32x4*)&s_doc[cur][lrow * KC + p0 * 4];
            const f32x4 v1 = *(const f32x4*)&s_doc[cur][lrow * KC + p1 * 4];
            if (r1) ssq[t] += v0.x * v0.x + v0.y * v0.y + v0.z * v0.z + v0.w * v0.w;
            if (r2) ssq[t] += v1.x * v1.x + v1.y * v1.y + v1.z * v1.z + v1.w * v1.w;

            short8v bhi, blo;
            #pragma unroll
            for (int j = 0; j < 4; ++j) {
                unsigned short h0 = f2bf(v0[j]);
                unsigned short h1 = f2bf(v1[j]);
                bhi[j]     = (short)h0;
                bhi[j + 4] = (short)h1;
                blo[j]     = (short)f2bf(v0[j] - bf2f(h0));
                blo[j + 4] = (short)f2bf(v1[j] - bf2f(h1));
            }
            acc[0][t] = __builtin_amdgcn_mfma_f32_16x16x32_bf16(ah[0], bhi, acc[0][t], 0, 0, 0);
            acc[0][t] = __builtin_amdgcn_mfma_f32_16x16x32_bf16(ah[0], blo, acc[0][t], 0, 0, 0);
            acc[0][t] = __builtin_amdgcn_mfma_f32_16x16x32_bf16(al[0], bhi, acc[0][t], 0, 0, 0);
            if (nqt > 1) {
                acc[1][t] = __builtin_amdgcn_mfma_f32_16x16x32_bf16(ah[1], bhi, acc[1][t], 0, 0, 0);
                acc[1][t] = __builtin_amdgcn_mfma_f32_16x16x32_bf16(ah[1], blo, acc[1][t], 0, 0, 0);
                acc[1][t] = __builtin_amdgcn_mfma_f32_16x16x32_bf16(al[1], bhi, acc[1][t], 0, 0, 0);
            }
        }
        __builtin_amdgcn_s_barrier();     // all reads done before buffer re-staged
        cur ^= 1;
    }

    // full row-norms: combine the 4 k-window partials (lanes l, l^16, l^32)
    float rinv[2];
    #pragma unroll
    for (int t = 0; t < 2; ++t) {
        float s = ssq[t];
        s += __shfl_xor(s, 16);
        s += __shfl_xor(s, 32);
        rinv[t] = 1.0f / sqrtf(s);        // row (l15) of tile t
    }

    // histogram in LDS, aliasing s_doc (dead after the loop's final barrier)
    int* hist = (int*)&s_doc[0][0];       // [QQ][32]
    for (int s = tid; s < QQ * 32; s += 256) hist[s] = 0;
    __syncthreads();

    // D layout (m89-verified): col = lane&15 (= d in tile), row = (lane>>4)*4 + reg (= q)
    #pragma unroll
    for (int qt = 0; qt < 2; ++qt) {
        #pragma unroll
        for (int r = 0; r < 4; ++r) {
            const int q = qt * 16 + l4 * 4 + r;
            if (q < len) {
                #pragma unroll
                for (int t = 0; t < 2; ++t) {
                    float sim = acc[qt][t][r] * rinv[t];
                    int bin = (int)floorf((sim + 1.0f) * 15.0f);
                    bin = bin < 0 ? 0 : (bin > 29 ? 29 : bin);
                    atomicAdd(&hist[q * 32 + bin], 1);
                }
            }
        }
    }
    __syncthreads();

    for (int s = tid; s < QQ * NB; s += 256) {
        const int q = s / NB, bin = s % NB;
        int tot = hist[q * 32 + bin];
        if (tot) atomicAdd(&ghist[((size_t)b * QQ + q) * NB + bin], tot);
    }
}

// ---------------- final: log1p + FFN + softmax gate + weighted sum ----------------
__global__ __launch_bounds__(64) void drmm_final(const int* __restrict__ ghist,
                                                 const float* __restrict__ glog,
                                                 const float* __restrict__ W1,
                                                 const float* __restrict__ b1,
                                                 const float* __restrict__ W2,
                                                 const float* __restrict__ b2,
                                                 const float* __restrict__ W3,
                                                 const float* __restrict__ b3,
                                                 float* __restrict__ out) {
    const int b = blockIdx.x;
    const int lane = threadIdx.x;         // lanes 0..31 carry q
    float z = 0.f, lg = -1e30f;
    if (lane < QQ) {
        const int* hrow = ghist + ((size_t)b * QQ + lane) * NB;
        float h[NB];
        #pragma unroll
        for (int v = 0; v < NB; ++v) h[v] = log1pf((float)hrow[v]);
        float t1[5];
        #pragma unroll
        for (int u = 0; u < 5; ++u) {
            float s = b1[u];
            #pragma unroll
            for (int v = 0; v < NB; ++v) s += W1[u * NB + v] * h[v];
            t1[u] = tanhf(s);
        }
        float s2 = b2[0];
        #pragma unroll
        for (int u = 0; u < 5; ++u) s2 += W2[u] * t1[u];
        z = tanhf(W3[0] * tanhf(s2) + b3[0]);
        lg = glog[b * QQ + lane];
    }
    float m = lg;
    for (int o = 16; o >= 1; o >>= 1) m = fmaxf(m, __shfl_xor(m, o));
    float e = (lane < QQ) ? expf(lg - m) : 0.f;
    float s = e;
    for (int o = 16; o >= 1; o >>= 1) s += __shfl_xor(s, o);
    float w = z * (e / s);
    for (int o = 16; o >= 1; o >>= 1) w += __shfl_xor(w, o);
    if (lane == 0) out[b] = w;
}

extern "C" void kernel_launch(void* const* d_in, const int* in_sizes, int n_in,
                              void* d_out, int out_size, void* d_ws, size_t ws_size,
                              hipStream_t stream) {
    const float* query = (const float*)d_in[0];
    const float* doc   = (const float*)d_in[1];
    const int*   qlen  = (const int*)d_in[2];
    const float* W1    = (const float*)d_in[3];
    const float* b1    = (const float*)d_in[4];
    const float* W2    = (const float*)d_in[5];
    const float* b2    = (const float*)d_in[6];
    const float* W3    = (const float*)d_in[7];
    const float* b3    = (const float*)d_in[8];
    const float* Wg    = (const float*)d_in[9];
    const float* bg    = (const float*)d_in[10];
    float* out = (float*)d_out;

    unsigned short* qh = (unsigned short*)d_ws;            // [2048][320] bf16 hi
    unsigned short* ql = qh + (size_t)BB * QQ * EPAD;      // [2048][320] bf16 lo
    float* glog = (float*)(ql + (size_t)BB * QQ * EPAD);   // [2048]
    int*   hist = (int*)(glog + BB * QQ);                  // [64][32][30]

    hipLaunchKernelGGL(drmm_prep, dim3(BB * QQ), dim3(64), 0, stream,
                       query, Wg, bg, qh, ql, glog, hist);
    hipLaunchKernelGGL(drmm_main, dim3(BB * NDT), dim3(256), 0, stream,
                       doc, qlen, qh, ql, hist);
    hipLaunchKernelGGL(drmm_final, dim3(BB), dim3(64), 0, stream,
                       hist, glog, W1, b1, W2, b2, W3, b3, out);
}